// Round 4
// baseline (279.279 us; speedup 1.0000x reference)
//
#include <hip/hip_runtime.h>
#include <hip/hip_bf16.h>
#include <cstdint>
#include <cstddef>

#define T_TOK 2048
#define HDIM  1024
#define FDIM  2048
#define NEXP  8
#define BM    128

typedef __attribute__((ext_vector_type(8))) short bf16x8;
typedef __attribute__((ext_vector_type(4))) float f32x4;

__device__ __forceinline__ unsigned short f2b(float f) {
  __hip_bfloat16 h = __float2bfloat16(f);
  return __builtin_bit_cast(unsigned short, h);
}

__device__ __forceinline__ void gload16(const void* g, void* l) {
  __builtin_amdgcn_global_load_lds(
      (const __attribute__((address_space(1))) unsigned int*)g,
      (__attribute__((address_space(3))) unsigned int*)l, 16, 0, 0);
}

__device__ __forceinline__ void cvt8(const float* __restrict__ s,
                                     unsigned short* __restrict__ d, int i) {
  const float4 f0 = ((const float4*)s)[2 * i];
  const float4 f1 = ((const float4*)s)[2 * i + 1];
  union { unsigned short u[8]; uint4 v; } p;
  p.u[0] = f2b(f0.x); p.u[1] = f2b(f0.y); p.u[2] = f2b(f0.z); p.u[3] = f2b(f0.w);
  p.u[4] = f2b(f1.x); p.u[5] = f2b(f1.y); p.u[6] = f2b(f1.z); p.u[7] = f2b(f1.w);
  ((uint4*)d)[i] = p.v;
}

// ---------------- router + sparsemixer + x->bf16, fused wg/wu conversion ----
__global__ __launch_bounds__(256) void router_k(
    const float* __restrict__ x, const float* __restrict__ rw,
    float* __restrict__ wslot, int* __restrict__ rows,
    int* __restrict__ cnt, unsigned short* __restrict__ xb,
    const float* __restrict__ wg32, const float* __restrict__ wu32,
    unsigned short* __restrict__ wg16, unsigned short* __restrict__ wu16)
{
  const int bx = blockIdx.x;
  if (bx >= 512) {
    // conversion blocks: 512 for wg, 512 for wu. each tensor: 2,097,152 uint4s.
    const int b2 = bx - 512;
    const float* s = (b2 < 512) ? wg32 : wu32;
    unsigned short* d = (b2 < 512) ? wg16 : wu16;
    const int base = ((b2 & 511) * 256 + threadIdx.x);
#pragma unroll
    for (int it = 0; it < 16; ++it) cvt8(s, d, base + it * 131072);
    return;
  }
  const int wave = threadIdx.x >> 6, lane = threadIdx.x & 63;
  const int t = bx * 4 + wave;
  const float* xr = x + (size_t)t * HDIM;
  unsigned short* xbr = xb + (size_t)t * HDIM;
  float acc[NEXP];
#pragma unroll
  for (int e = 0; e < NEXP; ++e) acc[e] = 0.f;
  for (int i = 0; i < HDIM / 64; ++i) {
    const int h = i * 64 + lane;
    const float xv = xr[h];
    xbr[h] = f2b(xv);
#pragma unroll
    for (int e = 0; e < NEXP; ++e) acc[e] += xv * rw[e * HDIM + h];
  }
#pragma unroll
  for (int e = 0; e < NEXP; ++e) {
#pragma unroll
    for (int off = 32; off; off >>= 1) acc[e] += __shfl_xor(acc[e], off);
  }
  if (lane == 0) {
    float m1 = acc[0]; int i1 = 0;
#pragma unroll
    for (int e = 1; e < NEXP; ++e) if (acc[e] > m1) { m1 = acc[e]; i1 = e; }
    float sum1 = 0.f;
#pragma unroll
    for (int e = 0; e < NEXP; ++e) {
      const float f = fmaxf(fabsf(acc[e]), m1);
      if (m1 - acc[e] <= 0.02f * f) sum1 += expf(acc[e] - m1);
    }
    float m2 = -3.4e38f; int i2 = 0;
#pragma unroll
    for (int e = 0; e < NEXP; ++e)
      if (e != i1 && acc[e] > m2) { m2 = acc[e]; i2 = e; }
    float sum2 = 0.f;
#pragma unroll
    for (int e = 0; e < NEXP; ++e) {
      if (e == i1) continue;
      const float f = fmaxf(fabsf(acc[e]), m2);
      if (m2 - acc[e] <= 0.02f * f) sum2 += expf(acc[e] - m2);
    }
    wslot[2 * t]     = 1.f / sum1;
    wslot[2 * t + 1] = 1.f / sum2;
    int p1 = atomicAdd(&cnt[i1], 1); rows[i1 * T_TOK + p1] = 2 * t;
    int p2 = atomicAdd(&cnt[i2], 1); rows[i2 * T_TOK + p2] = 2 * t + 1;
  }
}

// ---------------- gate/up GEMM (BK=32, dbuf, frag-major LDS) + fused wd conv ----
// LDS chunk layout: tile = [chunk][lane][16B]; A chunk c=(wr*4+mf), B chunk c=(wc*2+nf).
__global__ __launch_bounds__(256) void gemm_gateup_k(
    const unsigned short* __restrict__ xb,
    const unsigned short* __restrict__ wg16, const unsigned short* __restrict__ wu16,
    const int* __restrict__ rows, const int* __restrict__ cnt,
    const float* __restrict__ wslot, unsigned short* __restrict__ hbuf,
    const float* __restrict__ wd32, unsigned short* __restrict__ wd16)
{
  const int bx = blockIdx.x;
  if (bx >= 4096) {
    const int base = (bx - 4096) * 256 + threadIdx.x;   // 256 blocks convert wd
#pragma unroll
    for (int it = 0; it < 32; ++it) cvt8(wd32, wd16, base + it * 65536);
    return;
  }
  const int e  = bx >> 9;
  const int rm = bx & 511;
  const int mt = rm >> 5;
  const int nt = rm & 31;
  const int cnt_e = cnt[e];
  if (mt * BM >= cnt_e) return;

  __shared__ unsigned short As[2][4096];   // 8 chunks x 512
  __shared__ unsigned short Bg[2][2048];   // 4 chunks x 512
  __shared__ unsigned short Bu[2][2048];
  __shared__ int ldsRow[BM];

  const int tid = threadIdx.x;
  if (tid < BM) {
    const int idx = mt * BM + tid;
    ldsRow[tid] = (idx < cnt_e) ? rows[e * T_TOK + idx] : -1;
  }
  __syncthreads();

  const int lane = tid & 63, w = tid >> 6;
  const int wr = w >> 1, wc = w & 1;
  const int lr = lane & 15, lq = lane >> 4;

  // ---- staging sources (frag-major): A chunks c = it*4+w, it in {0,1} ----
  const unsigned short* aS[2];
  int aOff[2];
#pragma unroll
  for (int it = 0; it < 2; ++it) {
    const int c = it * 4 + w;
    const int row = (c >> 2) * 64 + (c & 3) * 16 + lr;   // lr = lane&15
    int r = ldsRow[row]; if (r < 0) r = 0;
    aS[it] = xb + (size_t)(r >> 1) * HDIM + lq * 8;
    aOff[it] = c * 512 + lane * 8;
  }
  // B chunks c = w
  const int rowB = (w >> 1) * 32 + (w & 1) * 16 + lr;
  const unsigned short* gS = wg16 + ((size_t)e * FDIM + nt * 64 + rowB) * HDIM + lq * 8;
  const unsigned short* uS = wu16 + ((size_t)e * FDIM + nt * 64 + rowB) * HDIM + lq * 8;
  const int bOff = w * 512 + lane * 8;

  f32x4 accg[4][2], accu[4][2];
#pragma unroll
  for (int mf = 0; mf < 4; ++mf)
#pragma unroll
    for (int nf = 0; nf < 2; ++nf) {
      accg[mf][nf] = (f32x4){0.f, 0.f, 0.f, 0.f};
      accu[mf][nf] = (f32x4){0.f, 0.f, 0.f, 0.f};
    }

  // prologue: stage k=0 into buf 0
  gload16(aS[0], &As[0][aOff[0]]);
  gload16(aS[1], &As[0][aOff[1]]);
  gload16(gS, &Bg[0][bOff]);
  gload16(uS, &Bu[0][bOff]);
  __syncthreads();

  int cur = 0;
  for (int k = 0; k < 32; ++k) {          // K = 1024 / 32
    const int nxt = cur ^ 1;
    if (k + 1 < 32) {
      const int ko = (k + 1) * 32;
      gload16(aS[0] + ko, &As[nxt][aOff[0]]);
      gload16(aS[1] + ko, &As[nxt][aOff[1]]);
      gload16(gS + ko, &Bg[nxt][bOff]);
      gload16(uS + ko, &Bu[nxt][bOff]);
    }
    bf16x8 a[4], bg[2], bu[2];
#pragma unroll
    for (int mf = 0; mf < 4; ++mf)
      a[mf] = *(const bf16x8*)&As[cur][(wr * 4 + mf) * 512 + lane * 8];
#pragma unroll
    for (int nf = 0; nf < 2; ++nf) {
      bg[nf] = *(const bf16x8*)&Bg[cur][(wc * 2 + nf) * 512 + lane * 8];
      bu[nf] = *(const bf16x8*)&Bu[cur][(wc * 2 + nf) * 512 + lane * 8];
    }
#pragma unroll
    for (int mf = 0; mf < 4; ++mf)
#pragma unroll
      for (int nf = 0; nf < 2; ++nf) {
        accg[mf][nf] = __builtin_amdgcn_mfma_f32_16x16x32_bf16(a[mf], bg[nf], accg[mf][nf], 0, 0, 0);
        accu[mf][nf] = __builtin_amdgcn_mfma_f32_16x16x32_bf16(a[mf], bu[nf], accu[mf][nf], 0, 0, 0);
      }
    __syncthreads();   // drains vmcnt(0): next buf staged, cur buf free
    cur = nxt;
  }

  // epilogue: h = silu(g)*u*w
#pragma unroll
  for (int mf = 0; mf < 4; ++mf)
#pragma unroll
    for (int nf = 0; nf < 2; ++nf) {
      const int col = nt * 64 + wc * 32 + nf * 16 + lr;
#pragma unroll
      for (int i = 0; i < 4; ++i) {
        const int lrow = wr * 64 + mf * 16 + lq * 4 + i;
        const int r = ldsRow[lrow];
        if (r < 0) continue;
        const float g = accg[mf][nf][i], u = accu[mf][nf][i];
        const float val = g / (1.f + __expf(-g)) * u * wslot[r];
        hbuf[(size_t)r * FDIM + col] = f2b(val);
      }
    }
}

// ---------------- down GEMM (BK=64, dbuf, frag-major LDS), plain stores ----
// A chunk c = wr*8+mf*2+ks (16), B chunk c = wc*4+nf*2+ks (8)
__global__ __launch_bounds__(256) void gemm_down_k(
    const unsigned short* __restrict__ hbuf,
    const unsigned short* __restrict__ wd16,
    const int* __restrict__ rows, const int* __restrict__ cnt,
    float* __restrict__ obuf)
{
  const int bx = blockIdx.x;
  const int e  = bx >> 8;
  const int rm = bx & 255;
  const int mt = rm >> 4;
  const int nt = rm & 15;
  const int cnt_e = cnt[e];
  if (mt * BM >= cnt_e) return;

  __shared__ unsigned short As[2][8192];   // 16 chunks x 512
  __shared__ unsigned short Bs[2][4096];   // 8 chunks x 512
  __shared__ int ldsRow[BM];

  const int tid = threadIdx.x;
  if (tid < BM) {
    const int idx = mt * BM + tid;
    ldsRow[tid] = (idx < cnt_e) ? rows[e * T_TOK + idx] : -1;
  }
  __syncthreads();

  const int lane = tid & 63, w = tid >> 6;
  const int wr = w >> 1, wc = w & 1;
  const int lr = lane & 15, lq = lane >> 4;

  const unsigned short* aS[4];
  int aOff[4];
#pragma unroll
  for (int it = 0; it < 4; ++it) {
    const int c = it * 4 + w;                       // 0..15
    const int row = (c >> 3) * 64 + ((c >> 1) & 3) * 16 + lr;
    const int col = (c & 1) * 32 + lq * 8;
    int r = ldsRow[row]; if (r < 0) r = 0;
    aS[it] = hbuf + (size_t)r * FDIM + col;
    aOff[it] = c * 512 + lane * 8;
  }
  const unsigned short* bS[2];
  int bOff[2];
#pragma unroll
  for (int it = 0; it < 2; ++it) {
    const int c = it * 4 + w;                       // 0..7
    const int row = (c >> 2) * 32 + ((c >> 1) & 1) * 16 + lr;
    const int col = (c & 1) * 32 + lq * 8;
    bS[it] = wd16 + ((size_t)e * HDIM + nt * 64 + row) * FDIM + col;
    bOff[it] = c * 512 + lane * 8;
  }

  f32x4 acc[4][2];
#pragma unroll
  for (int mf = 0; mf < 4; ++mf)
#pragma unroll
    for (int nf = 0; nf < 2; ++nf) acc[mf][nf] = (f32x4){0.f, 0.f, 0.f, 0.f};

  gload16(aS[0], &As[0][aOff[0]]);
  gload16(aS[1], &As[0][aOff[1]]);
  gload16(aS[2], &As[0][aOff[2]]);
  gload16(aS[3], &As[0][aOff[3]]);
  gload16(bS[0], &Bs[0][bOff[0]]);
  gload16(bS[1], &Bs[0][bOff[1]]);
  __syncthreads();

  int cur = 0;
  for (int k = 0; k < 32; ++k) {          // K = 2048 / 64
    const int nxt = cur ^ 1;
    if (k + 1 < 32) {
      const int ko = (k + 1) * 64;
      gload16(aS[0] + ko, &As[nxt][aOff[0]]);
      gload16(aS[1] + ko, &As[nxt][aOff[1]]);
      gload16(aS[2] + ko, &As[nxt][aOff[2]]);
      gload16(aS[3] + ko, &As[nxt][aOff[3]]);
      gload16(bS[0] + ko, &Bs[nxt][bOff[0]]);
      gload16(bS[1] + ko, &Bs[nxt][bOff[1]]);
    }
    bf16x8 a[4][2], b[2][2];
#pragma unroll
    for (int mf = 0; mf < 4; ++mf)
#pragma unroll
      for (int ks = 0; ks < 2; ++ks)
        a[mf][ks] = *(const bf16x8*)&As[cur][(wr * 8 + mf * 2 + ks) * 512 + lane * 8];
#pragma unroll
    for (int nf = 0; nf < 2; ++nf)
#pragma unroll
      for (int ks = 0; ks < 2; ++ks)
        b[nf][ks] = *(const bf16x8*)&Bs[cur][(wc * 4 + nf * 2 + ks) * 512 + lane * 8];
#pragma unroll
    for (int mf = 0; mf < 4; ++mf)
#pragma unroll
      for (int nf = 0; nf < 2; ++nf)
#pragma unroll
        for (int ks = 0; ks < 2; ++ks)
          acc[mf][nf] = __builtin_amdgcn_mfma_f32_16x16x32_bf16(a[mf][ks], b[nf][ks], acc[mf][nf], 0, 0, 0);
    __syncthreads();
    cur = nxt;
  }

#pragma unroll
  for (int mf = 0; mf < 4; ++mf)
#pragma unroll
    for (int nf = 0; nf < 2; ++nf) {
      const int col = nt * 64 + wc * 32 + nf * 16 + lr;
#pragma unroll
      for (int i = 0; i < 4; ++i) {
        const int lrow = wr * 64 + mf * 16 + lq * 4 + i;
        const int r = ldsRow[lrow];
        if (r < 0) continue;
        obuf[(size_t)r * HDIM + col] = acc[mf][nf][i];
      }
    }
}

// ---------------- combine: out[t] = obuf[2t] + obuf[2t+1] ----------------
__global__ __launch_bounds__(256) void combine_k(const float* __restrict__ obuf,
                                                 float* __restrict__ out)
{
  const int i = blockIdx.x * 256 + threadIdx.x;
  const int t = i >> 8, c = i & 255;
  const float4* o4 = (const float4*)obuf;
  const float4 a = o4[(size_t)(2 * t) * (HDIM / 4) + c];
  const float4 b = o4[(size_t)(2 * t + 1) * (HDIM / 4) + c];
  float4 r; r.x = a.x + b.x; r.y = a.y + b.y; r.z = a.z + b.z; r.w = a.w + b.w;
  ((float4*)out)[i] = r;
}

extern "C" void kernel_launch(void* const* d_in, const int* in_sizes, int n_in,
                              void* d_out, int out_size, void* d_ws, size_t ws_size,
                              hipStream_t stream) {
  const float* x  = (const float*)d_in[0];
  const float* rw = (const float*)d_in[1];
  const float* wg = (const float*)d_in[2];
  const float* wu = (const float*)d_in[3];
  const float* wd = (const float*)d_in[4];
  float* out = (float*)d_out;

  char* ws = (char*)d_ws;
  unsigned short* hbuf = (unsigned short*)ws;                        // 16 MiB
  unsigned short* xb   = (unsigned short*)(ws + (16u << 20));        // 4 MiB
  int*   cnt   = (int*)  (ws + (20u << 20));                         // 256 B
  int*   rows  = (int*)  (ws + (20u << 20) + 256);                   // 64 KiB
  float* wslot = (float*)(ws + (20u << 20) + 256 + 65536);           // 16 KiB
  unsigned short* wg16 = (unsigned short*)(ws + (24ull << 20));      // 32 MiB
  unsigned short* wu16 = (unsigned short*)(ws + (56ull << 20));      // 32 MiB
  unsigned short* wd16 = (unsigned short*)(ws + (88ull << 20));      // 32 MiB
  float* obuf = (float*)(ws + (24ull << 20));   // 16 MiB, reuses wg16 (dead after gateup)

  hipMemsetAsync(cnt, 0, 256, stream);
  router_k<<<512 + 1024, 256, 0, stream>>>(x, rw, wslot, rows, cnt, xb, wg, wu, wg16, wu16);
  gemm_gateup_k<<<4096 + 256, 256, 0, stream>>>(xb, wg16, wu16, rows, cnt, wslot, hbuf, wd, wd16);
  gemm_down_k<<<2048, 256, 0, stream>>>(hbuf, wd16, rows, cnt, obuf);
  combine_k<<<T_TOK * HDIM / 4 / 256, 256, 0, stream>>>(obuf, out);
}